// Round 16
// baseline (361.824 us; speedup 1.0000x reference)
//
#include <hip/hip_runtime.h>
#include <hip/hip_bf16.h>

typedef __bf16 bf16;
typedef __bf16 bf16x8 __attribute__((ext_vector_type(8)));
typedef float f32x4 __attribute__((ext_vector_type(4)));
typedef unsigned int u32x4 __attribute__((ext_vector_type(4)));

#define DD 2048
#define DD2 4194304ull
#define G9_LDS 131072   // gemm9: 2 buffers x (A[256][64] + B[256][64]) bf16
#define G10_LDS 65536   // gemm10: 2 buffers x (A[128][64] + B[128][64]) bf16

__device__ __forceinline__ void glds16(const void* g, void* l) {
  __builtin_amdgcn_global_load_lds((const __attribute__((address_space(1))) void*)g,
                                   (__attribute__((address_space(3))) void*)l, 16, 0, 0);
}

__device__ __forceinline__ f32x4 mfma16(bf16x8 a, bf16x8 b, f32x4 c) {
  return __builtin_amdgcn_mfma_f32_16x16x32_bf16(a, b, c, 0, 0, 0);
}

__device__ __forceinline__ unsigned pk2(float lo, float hi) {
  unsigned short a = __builtin_bit_cast(unsigned short, (bf16)lo);
  unsigned short b = __builtin_bit_cast(unsigned short, (bf16)hi);
  return (unsigned)a | ((unsigned)b << 16);
}

// cvt helper: grid-stride fp32->bf16 over 4 segments of (1<<seglog) elems, nb blocks
__device__ __forceinline__ void cvt_body(const float* s0, const float* s1, const float* s2,
                                         const float* s3, bf16* dst, int seglog, size_t total,
                                         int bid, int nb) {
  size_t i = ((size_t)bid * 256 + threadIdx.x) * 16;
  const size_t stride = (size_t)nb * 256 * 16;
  for (; i < total; i += stride) {
    int seg = (int)(i >> seglog);
    const float* src = (seg == 0) ? s0 : (seg == 1) ? s1 : (seg == 2) ? s2 : s3;
    size_t loc = i - ((size_t)seg << seglog);
    float4 a0 = *(const float4*)(src + loc);
    float4 a1 = *(const float4*)(src + loc + 4);
    float4 a2 = *(const float4*)(src + loc + 8);
    float4 a3 = *(const float4*)(src + loc + 12);
    bf16x8 o0, o1;
    o0[0] = (bf16)a0.x; o0[1] = (bf16)a0.y; o0[2] = (bf16)a0.z; o0[3] = (bf16)a0.w;
    o0[4] = (bf16)a1.x; o0[5] = (bf16)a1.y; o0[6] = (bf16)a1.z; o0[7] = (bf16)a1.w;
    o1[0] = (bf16)a2.x; o1[1] = (bf16)a2.y; o1[2] = (bf16)a2.z; o1[3] = (bf16)a2.w;
    o1[4] = (bf16)a3.x; o1[5] = (bf16)a3.y; o1[6] = (bf16)a3.z; o1[7] = (bf16)a3.w;
    *(bf16x8*)(dst + i) = o0;
    *(bf16x8*)(dst + i + 8) = o1;
  }
}

// ---------------- pre_k: cvt(wq..wo) [blocks 0..2047]  ||  prenorm-blend [2048..4095] ----------------
__global__ __launch_bounds__(256) void pre_k(const float* __restrict__ wq, const float* __restrict__ wk,
                                             const float* __restrict__ wv, const float* __restrict__ wo,
                                             bf16* __restrict__ wdst,
                                             const float* __restrict__ x, const float* __restrict__ x0,
                                             const float* __restrict__ lambdas, bf16* __restrict__ xn) {
  if (blockIdx.x < 2048) {
    cvt_body(wq, wk, wv, wo, wdst, 22, 4 * DD2, blockIdx.x, 2048);
    return;
  }
  const int t = blockIdx.x - 2048, tid = threadIdx.x;
  const float4* xr = (const float4*)(x + (size_t)t * DD);
  float4 a0 = xr[2 * tid], a1 = xr[2 * tid + 1];
  float v[8] = {a0.x, a0.y, a0.z, a0.w, a1.x, a1.y, a1.z, a1.w};
  const float l0 = lambdas[0], l1 = lambdas[1];
  const float4* yr = (const float4*)(x0 + (size_t)t * DD);
  float4 b0 = yr[2 * tid], b1 = yr[2 * tid + 1];
  float w[8] = {b0.x, b0.y, b0.z, b0.w, b1.x, b1.y, b1.z, b1.w};
#pragma unroll
  for (int i = 0; i < 8; ++i) v[i] = l0 * v[i] + l1 * w[i];
  float ss = 0.f;
#pragma unroll
  for (int i = 0; i < 8; ++i) ss += v[i] * v[i];
#pragma unroll
  for (int off = 1; off < 64; off <<= 1) ss += __shfl_xor(ss, off, 64);
  __shared__ float red[4];
  if ((tid & 63) == 0) red[tid >> 6] = ss;
  __syncthreads();
  ss = red[0] + red[1] + red[2] + red[3];
  const float sc = rsqrtf(ss * (1.0f / DD) + 1.1920928955078125e-07f);
  bf16x8 o;
#pragma unroll
  for (int i = 0; i < 8; ++i) o[i] = (bf16)(v[i] * sc);
  *(bf16x8*)(xn + (size_t)t * DD + tid * 8) = o;
}

// ---------------- ropevt_k: rope [0..16383] || V-transpose [16384..18431] ----------------
__global__ __launch_bounds__(256) void ropevt_k(bf16* __restrict__ qg, bf16* __restrict__ kg,
                                                const bf16* __restrict__ v, bf16* __restrict__ vt) {
  __shared__ alignas(16) bf16 tile[16 * 128];
  if (blockIdx.x < 16384) {
    const int tid = threadIdx.x, lane = tid & 63, wid = tid >> 6;
    const int p = blockIdx.x * 4 + wid;          // [arr(2)][t(2048)][h(16)]
    bf16* base = ((p >> 15) ? kg : qg);
    const int t = (p >> 4) & 2047, hh = p & 15;
    base += (size_t)t * DD + hh * 128;
    float x1 = (float)base[lane], x2 = (float)base[lane + 64];
    float ss = x1 * x1 + x2 * x2;
#pragma unroll
    for (int off = 1; off < 64; off <<= 1) ss += __shfl_xor(ss, off, 64);
    const float sc = rsqrtf(ss * (1.0f / 128.0f) + 1.1920928955078125e-07f);
    x1 *= sc; x2 *= sc;
    const float fr = (float)t * exp2f((float)lane * (-13.287712379549449f / 64.0f));
    const float s = sinf(fr), c = cosf(fr);
    base[lane]      = (bf16)(x1 * c + x2 * s);
    base[lane + 64] = (bf16)(-x1 * s + x2 * c);
    return;
  }
  const int b = blockIdx.x - 16384;              // 0..2047
  const int tb = b & 127, hb = b >> 7, tid = threadIdx.x;
  glds16(v + (size_t)(tb * 16 + (tid >> 4)) * DD + hb * 128 + (tid & 15) * 8, tile + tid * 8);
  __syncthreads();
  const int d_l = tid & 127, tc = tid >> 7;
  bf16x8 o;
#pragma unroll
  for (int i = 0; i < 8; ++i) o[i] = tile[(tc * 8 + i) * 128 + d_l];
  *(bf16x8*)(vt + (size_t)(hb * 128 + d_l) * DD + tb * 16 + tc * 8) = o;
}

// ================ gemm9: 256x256 tile, 8-wave deep pipeline (R7) ================
__device__ __forceinline__ void g9_stageA(const bf16* A, int Kstride, int row0, int k0,
                                          bf16* buf, int hm, int tid) {
#pragma unroll
  for (int i = 0; i < 2; ++i) {
    int e = tid + i * 512;                 // [0,1024): prl = e>>3, slot = e&7
    int prl = e >> 3, slot = e & 7;
    int wm = prl >> 6, r63 = prl & 63;
    glds16(A + (size_t)(row0 + wm * 128 + hm * 64 + r63) * Kstride + k0 + ((slot ^ (prl & 7)) * 8),
           buf + hm * 8192 + e * 8);
  }
}
__device__ __forceinline__ void g9_stageB(const bf16* B, int Kstride, int col0, int k0,
                                          bf16* buf, int hn, int tid) {
#pragma unroll
  for (int i = 0; i < 2; ++i) {
    int e = tid + i * 512;
    int pbl = e >> 3, slot = e & 7;
    int wn = pbl >> 5, q = pbl & 31;
    glds16(B + (size_t)(col0 + wn * 64 + hn * 32 + q) * Kstride + k0 + ((slot ^ (pbl & 7)) * 8),
           buf + 16384 + hn * 8192 + e * 8);
  }
}

__device__ __forceinline__ void gemm9_core(const bf16* __restrict__ A, const bf16* __restrict__ B,
                                           int Kstride, int Klen, int row0, int col0,
                                           bf16* smem, f32x4 (&acc)[8][4]) {
  const int tid = threadIdx.x, lane = tid & 63, wid = tid >> 6;
  const int wm = wid >> 2, wn = wid & 3;
  const int l15 = lane & 15, g = lane >> 4;
  const int sw = l15 & 7;
  const int NT = Klen >> 6;
  g9_stageA(A, Kstride, row0, 0, smem, 0, tid);
  g9_stageB(B, Kstride, col0, 0, smem, 0, tid);
  g9_stageB(B, Kstride, col0, 0, smem, 1, tid);
  g9_stageA(A, Kstride, row0, 0, smem, 1, tid);
  g9_stageA(A, Kstride, row0, 64, smem + 32768, 0, tid);
  g9_stageB(B, Kstride, col0, 64, smem + 32768, 0, tid);
  asm volatile("s_waitcnt vmcnt(8)" ::: "memory");
  __builtin_amdgcn_s_barrier();

  bf16x8 a[4][2], b0[2][2], b1[2][2];
  for (int t = 0; t < NT; ++t) {
    bf16* cb = smem + (t & 1) * 32768;
    bf16* nb = smem + ((t + 1) & 1) * 32768;
    const bool s1 = (t + 1) < NT, s2 = (t + 2) < NT;
    // ---- P1
#pragma unroll
    for (int mm = 0; mm < 4; ++mm)
#pragma unroll
      for (int ks = 0; ks < 2; ++ks)
        a[mm][ks] = *(const bf16x8*)(cb + (wm * 64 + mm * 16 + l15) * 64 + (((ks * 4 + g) ^ sw) * 8));
#pragma unroll
    for (int nn = 0; nn < 2; ++nn)
#pragma unroll
      for (int ks = 0; ks < 2; ++ks)
        b0[nn][ks] = *(const bf16x8*)(cb + 16384 + (wn * 32 + nn * 16 + l15) * 64 + (((ks * 4 + g) ^ sw) * 8));
    if (s1) { g9_stageB(B, Kstride, col0, (t + 1) << 6, nb, 1, tid);
              g9_stageA(A, Kstride, row0, (t + 1) << 6, nb, 1, tid);
              asm volatile("s_waitcnt vmcnt(8)" ::: "memory"); }
    else    { asm volatile("s_waitcnt vmcnt(0)" ::: "memory"); }
    __builtin_amdgcn_s_barrier();
    __builtin_amdgcn_s_setprio(1);
#pragma unroll
    for (int mm = 0; mm < 4; ++mm)
#pragma unroll
      for (int nn = 0; nn < 2; ++nn)
#pragma unroll
        for (int ks = 0; ks < 2; ++ks)
          acc[mm][nn] = mfma16(a[mm][ks], b0[nn][ks], acc[mm][nn]);
    __builtin_amdgcn_s_setprio(0);
    // ---- P2
#pragma unroll
    for (int nn = 0; nn < 2; ++nn)
#pragma unroll
      for (int ks = 0; ks < 2; ++ks)
        b1[nn][ks] = *(const bf16x8*)(cb + 16384 + 8192 + (wn * 32 + nn * 16 + l15) * 64 + (((ks * 4 + g) ^ sw) * 8));
    __builtin_amdgcn_s_barrier();
    __builtin_amdgcn_s_setprio(1);
#pragma unroll
    for (int mm = 0; mm < 4; ++mm)
#pragma unroll
      for (int nn = 0; nn < 2; ++nn)
#pragma unroll
        for (int ks = 0; ks < 2; ++ks)
          acc[mm][2 + nn] = mfma16(a[mm][ks], b1[nn][ks], acc[mm][2 + nn]);
    __builtin_amdgcn_s_setprio(0);
    // ---- P3
#pragma unroll
    for (int mm = 0; mm < 4; ++mm)
#pragma unroll
      for (int ks = 0; ks < 2; ++ks)
        a[mm][ks] = *(const bf16x8*)(cb + 8192 + (wm * 64 + mm * 16 + l15) * 64 + (((ks * 4 + g) ^ sw) * 8));
    __builtin_amdgcn_s_barrier();
    __builtin_amdgcn_s_setprio(1);
#pragma unroll
    for (int mm = 0; mm < 4; ++mm)
#pragma unroll
      for (int nn = 0; nn < 2; ++nn)
#pragma unroll
        for (int ks = 0; ks < 2; ++ks)
          acc[4 + mm][nn] = mfma16(a[mm][ks], b0[nn][ks], acc[4 + mm][nn]);
    __builtin_amdgcn_s_setprio(0);
    // ---- P4
    if (s2) { g9_stageA(A, Kstride, row0, (t + 2) << 6, cb, 0, tid);
              g9_stageB(B, Kstride, col0, (t + 2) << 6, cb, 0, tid);
              asm volatile("s_waitcnt vmcnt(8)" ::: "memory"); }
    else if (s1) { asm volatile("s_waitcnt vmcnt(4)" ::: "memory"); }
    __builtin_amdgcn_s_barrier();
    __builtin_amdgcn_s_setprio(1);
#pragma unroll
    for (int mm = 0; mm < 4; ++mm)
#pragma unroll
      for (int nn = 0; nn < 2; ++nn)
#pragma unroll
        for (int ks = 0; ks < 2; ++ks)
          acc[4 + mm][2 + nn] = mfma16(a[mm][ks], b1[nn][ks], acc[4 + mm][2 + nn]);
    __builtin_amdgcn_s_setprio(0);
  }
}

#define GEMM9_EPI(STMT)                                                        \
  { const int lane_ = threadIdx.x & 63, wid_ = threadIdx.x >> 6;               \
    const int l15_ = lane_ & 15, g_ = lane_ >> 4;                              \
    const int wm_ = wid_ >> 2, wn_ = wid_ & 3;                                 \
    _Pragma("unroll") for (int m = 0; m < 8; ++m)                              \
    _Pragma("unroll") for (int n = 0; n < 4; ++n)                              \
    _Pragma("unroll") for (int j = 0; j < 4; ++j) {                            \
      int grow = row0 + wm_ * 128 + (m >> 2) * 64 + (m & 3) * 16 + g_ * 4 + j; \
      int gcol = col0 + wn_ * 64 + (n >> 1) * 32 + (n & 1) * 16 + l15_;        \
      float vacc = acc[m][n][j];                                               \
      STMT; } }

__global__ __launch_bounds__(512, 1) void gemm9_qkv(const bf16* __restrict__ A,
    const bf16* __restrict__ Wq, const bf16* __restrict__ Wk, const bf16* __restrict__ Wv,
    bf16* __restrict__ oq, bf16* __restrict__ ok, bf16* __restrict__ ov,
    const float* __restrict__ vi, const float* __restrict__ lambp) {
  extern __shared__ bf16 smem9[];
  const int z = blockIdx.z;
  const bf16* B = (z == 0) ? Wq : (z == 1) ? Wk : Wv;
  bf16* out = (z == 0) ? oq : (z == 1) ? ok : ov;
  const int row0 = blockIdx.y * 256, col0 = blockIdx.x * 256;
  f32x4 acc[8][4] = {};
  gemm9_core(A, B, DD, DD, row0, col0, smem9, acc);
  if (z < 2) {
    GEMM9_EPI( out[(size_t)grow * DD + gcol] = (bf16)vacc; )
  } else {
    const float lam = *lambp;
    GEMM9_EPI( out[(size_t)grow * DD + gcol] =
                 (bf16)((1.0f - lam) * vacc + lam * vi[(size_t)grow * DD + gcol]); )
  }
}

__global__ __launch_bounds__(512, 1) void gemm9_relu(const bf16* __restrict__ A, const bf16* __restrict__ B,
                                                     bf16* __restrict__ out, int N, int Kstride, int Klen) {
  extern __shared__ bf16 smem9[];
  const int row0 = blockIdx.y * 256, col0 = blockIdx.x * 256;
  f32x4 acc[8][4] = {};
  gemm9_core(A, B, Kstride, Klen, row0, col0, smem9, acc);
  GEMM9_EPI( float r = fmaxf(vacc, 0.f); out[(size_t)grow * N + gcol] = (bf16)(r * r); )
}

__global__ __launch_bounds__(512, 1) void gemm9_part(const bf16* __restrict__ A, const bf16* __restrict__ B,
                                                     float* __restrict__ o1, float* __restrict__ o2,
                                                     int zsw, int N, int Kstride, int Klen) {
  extern __shared__ bf16 smem9[];
  const int row0 = blockIdx.y * 256, col0 = blockIdx.x * 256;
  const int z = blockIdx.z, kofs = z * Klen;
  float* out = (z < zsw) ? (o1 + (size_t)z * DD2) : (o2 + (size_t)(z - zsw) * DD2);
  f32x4 acc[8][4] = {};
  gemm9_core(A + kofs, B + kofs, Kstride, Klen, row0, col0, smem9, acc);
  GEMM9_EPI( out[(size_t)grow * N + gcol] = vacc; )
}

// ================ gemm10: 128x128 tile, 8-wave, 2-blocks/CU — wo only ================
__device__ __forceinline__ void g10_stageA(const bf16* A, int Kstride, int row0, int k0,
                                           bf16* buf, int hm, int tid) {
  int prl = tid >> 3, slot = tid & 7;
  int wmb = prl >> 5, r31 = prl & 31;
  glds16(A + (size_t)(row0 + wmb * 64 + hm * 32 + r31) * Kstride + k0 + ((slot ^ (prl & 7)) * 8),
         buf + hm * 4096 + tid * 8);
}
__device__ __forceinline__ void g10_stageB(const bf16* B, int Kstride, int col0, int k0,
                                           bf16* buf, int hn, int tid) {
  int pbl = tid >> 3, slot = tid & 7;
  int wnb = pbl >> 4, c15 = pbl & 15;
  glds16(B + (size_t)(col0 + wnb * 32 + hn * 16 + c15) * Kstride + k0 + ((slot ^ (pbl & 7)) * 8),
         buf + 8192 + hn * 4096 + tid * 8);
}

__device__ __forceinline__ void gemm10_core(const bf16* __restrict__ A, const bf16* __restrict__ B,
                                            int Kstride, int Klen, int row0, int col0,
                                            bf16* smem, f32x4 (&acc)[4][2]) {
  const int tid = threadIdx.x, lane = tid & 63, wid = tid >> 6;
  const int wm = wid >> 2, wn = wid & 3;
  const int l15 = lane & 15, g = lane >> 4;
  const int NT = Klen >> 6;
  g10_stageA(A, Kstride, row0, 0, smem, 0, tid);
  g10_stageB(B, Kstride, col0, 0, smem, 0, tid);
  g10_stageB(B, Kstride, col0, 0, smem, 1, tid);
  g10_stageA(A, Kstride, row0, 0, smem, 1, tid);
  asm volatile("s_waitcnt vmcnt(2)" ::: "memory");
  __builtin_amdgcn_s_barrier();

  bf16x8 a[2][2], b0[2], b1[2];
  for (int t = 0; t < NT; ++t) {
    bf16* cb = smem + (t & 1) * 16384;
    bf16* nb = smem + ((t + 1) & 1) * 16384;
    const int kst = (t + 1) << 6;
    const bool st = (t + 1) < NT;
    // ---- P1
#pragma unroll
    for (int mm = 0; mm < 2; ++mm)
#pragma unroll
      for (int ks = 0; ks < 2; ++ks) {
        int pr = wm * 32 + mm * 16 + l15;
        a[mm][ks] = *(const bf16x8*)(cb + pr * 64 + (((ks * 4 + g) ^ (pr & 7)) * 8));
      }
#pragma unroll
    for (int ks = 0; ks < 2; ++ks) {
      int pb = wn * 16 + l15;
      b0[ks] = *(const bf16x8*)(cb + 8192 + pb * 64 + (((ks * 4 + g) ^ (pb & 7)) * 8));
    }
    if (st) { g10_stageA(A, Kstride, row0, kst, nb, 0, tid);
              asm volatile("s_waitcnt vmcnt(2)" ::: "memory"); }
    else    { asm volatile("s_waitcnt vmcnt(1)" ::: "memory"); }
    __builtin_amdgcn_s_barrier();
    __builtin_amdgcn_s_setprio(1);
#pragma unroll
    for (int mm = 0; mm < 2; ++mm)
#pragma unroll
      for (int ks = 0; ks < 2; ++ks)
        acc[mm][0] = mfma16(a[mm][ks], b0[ks], acc[mm][0]);
    __builtin_amdgcn_s_setprio(0);
    // ---- P2
#pragma unroll
    for (int ks = 0; ks < 2; ++ks) {
      int pb = wn * 16 + l15;
      b1[ks] = *(const bf16x8*)(cb + 8192 + 4096 + pb * 64 + (((ks * 4 + g) ^ (pb & 7)) * 8));
    }
    if (st) { g10_stageB(B, Kstride, col0, kst, nb, 0, tid);
              asm volatile("s_waitcnt vmcnt(2)" ::: "memory"); }
    else    { asm volatile("s_waitcnt vmcnt(0)" ::: "memory"); }
    __builtin_amdgcn_s_barrier();
    __builtin_amdgcn_s_setprio(1);
#pragma unroll
    for (int mm = 0; mm < 2; ++mm)
#pragma unroll
      for (int ks = 0; ks < 2; ++ks)
        acc[mm][1] = mfma16(a[mm][ks], b1[ks], acc[mm][1]);
    __builtin_amdgcn_s_setprio(0);
    // ---- P3
#pragma unroll
    for (int mm = 0; mm < 2; ++mm)
#pragma unroll
      for (int ks = 0; ks < 2; ++ks) {
        int pr = 64 + wm * 32 + mm * 16 + l15;
        a[mm][ks] = *(const bf16x8*)(cb + pr * 64 + (((ks * 4 + g) ^ (pr & 7)) * 8));
      }
    if (st) g10_stageB(B, Kstride, col0, kst, nb, 1, tid);
    __builtin_amdgcn_s_barrier();
    __builtin_amdgcn_s_setprio(1);
#pragma unroll
    for (int mm = 0; mm < 2; ++mm)
#pragma unroll
      for (int ks = 0; ks < 2; ++ks)
        acc[2 + mm][0] = mfma16(a[mm][ks], b0[ks], acc[2 + mm][0]);
    __builtin_amdgcn_s_setprio(0);
    // ---- P4
    if (st) { g10_stageA(A, Kstride, row0, kst, nb, 1, tid);
              asm volatile("s_waitcnt vmcnt(2)" ::: "memory"); }
    __builtin_amdgcn_s_barrier();
    __builtin_amdgcn_s_setprio(1);
#pragma unroll
    for (int mm = 0; mm < 2; ++mm)
#pragma unroll
      for (int ks = 0; ks < 2; ++ks)
        acc[2 + mm][1] = mfma16(a[mm][ks], b1[ks], acc[2 + mm][1]);
    __builtin_amdgcn_s_setprio(0);
  }
}

#define GEMM10_EPI(STMT)                                                       \
  { const int lane_ = threadIdx.x & 63, wid_ = threadIdx.x >> 6;               \
    const int l15_ = lane_ & 15, g_ = lane_ >> 4;                              \
    const int wm_ = wid_ >> 2, wn_ = wid_ & 3;                                 \
    _Pragma("unroll") for (int m = 0; m < 4; ++m)                              \
    _Pragma("unroll") for (int n = 0; n < 2; ++n)                              \
    _Pragma("unroll") for (int j = 0; j < 4; ++j) {                            \
      int grow = row0 + wm_ * 64 + (m >> 1) * 32 + (m & 1) * 16 + g_ * 4 + j;  \
      int gcol = col0 + wn_ * 32 + n * 16 + l15_;                              \
      float vacc = acc[m][n][j];                                               \
      STMT; } }

__global__ __launch_bounds__(512, 4) void gemm10_part(const bf16* __restrict__ A, const bf16* __restrict__ B,
                                                      float* __restrict__ o1, int N, int Kstride, int Klen) {
  extern __shared__ bf16 smem10[];
  const int row0 = blockIdx.y * 128, col0 = blockIdx.x * 128;
  const int kofs = blockIdx.z * Klen;
  float* out = o1 + (size_t)blockIdx.z * DD2;
  f32x4 acc[4][2] = {};
  gemm10_core(A + kofs, B + kofs, Kstride, Klen, row0, col0, smem10, acc);
  GEMM10_EPI( out[(size_t)grow * N + gcol] = vacc; )
}

// -------- wored_cvt_k: wo_red+prenorm [blocks 0..2047] || cvt(wfc,wproj) [2048..4095] --------
__global__ __launch_bounds__(256) void wored_cvt_k(const float* __restrict__ pa,
                                                   float* __restrict__ a_f, bf16* __restrict__ an,
                                                   const float* __restrict__ wfc, const float* __restrict__ wpj,
                                                   bf16* __restrict__ wdst) {
  if (blockIdx.x >= 2048) {
    cvt_body(wfc, wpj, wfc, wfc, wdst, 24, 8 * DD2, blockIdx.x - 2048, 2048);
    return;
  }
  const int t = blockIdx.x, tid = threadIdx.x;
  const size_t base = (size_t)t * DD + tid * 8;
  float v[8];
#pragma unroll
  for (int h = 0; h < 2; ++h) {
    size_t i = base + h * 4;
    float4 r0 = *(const float4*)(pa + i);
    float4 r1 = *(const float4*)(pa + DD2 + i);
    v[h*4+0] = r0.x + r1.x;
    v[h*4+1] = r0.y + r1.y;
    v[h*4+2] = r0.z + r1.z;
    v[h*4+3] = r0.w + r1.w;
  }
  *(float4*)(a_f + base)     = make_float4(v[0], v[1], v[2], v[3]);
  *(float4*)(a_f + base + 4) = make_float4(v[4], v[5], v[6], v[7]);
  float ss = 0.f;
#pragma unroll
  for (int i = 0; i < 8; ++i) ss += v[i] * v[i];
#pragma unroll
  for (int off = 1; off < 64; off <<= 1) ss += __shfl_xor(ss, off, 64);
  __shared__ float red[4];
  if ((tid & 63) == 0) red[tid >> 6] = ss;
  __syncthreads();
  ss = red[0] + red[1] + red[2] + red[3];
  const float sc = rsqrtf(ss * (1.0f / DD) + 1.1920928955078125e-07f);
  bf16x8 o;
#pragma unroll
  for (int i = 0; i < 8; ++i) o[i] = (bf16)(v[i] * sc);
  *(bf16x8*)(an + base) = o;
}

// proj reduce: 4 partials (pa[0..2], pw) + residual a_f
__global__ __launch_bounds__(256) void proj_red(const float* __restrict__ pa, const float* __restrict__ pw,
                                                const float* __restrict__ a_f, float* __restrict__ out) {
  const size_t base = ((size_t)blockIdx.x * 256 + threadIdx.x) * 8;
#pragma unroll
  for (int h = 0; h < 2; ++h) {
    size_t i = base + h * 4;
    float4 r = *(const float4*)(a_f + i);
    float4 u = *(const float4*)(pa + i);
    float4 w = *(const float4*)(pa + DD2 + i);
    float4 z = *(const float4*)(pa + 2 * DD2 + i);
    float4 y = *(const float4*)(pw + i);
    *(float4*)(out + i) = make_float4(r.x + u.x + w.x + z.x + y.x,
                                      r.y + u.y + w.y + z.y + y.y,
                                      r.z + u.z + w.z + z.z + y.z,
                                      r.w + u.w + w.w + z.w + y.w);
  }
}

// ---------------- causal flash attention, KB=64, 2-buffer ----------------
// Ks[2][64k][128d] (16B slots swz by k&7); Vt[2][128d][64k] (8-elem chunks swz by d&7).
__device__ __forceinline__ void att_stageK64(const bf16* kg, int h, int kt, bf16* dst, int tid) {
#pragma unroll
  for (int r = 0; r < 4; ++r) {
    int e = tid + r * 256, row = e >> 4, slot = e & 15;
    glds16(kg + (size_t)(kt * 64 + row) * DD + h * 128 + ((slot ^ (row & 7)) * 8), dst + e * 8);
  }
}
__device__ __forceinline__ void att_stageV64(const bf16* vtg, int h, int kt, bf16* dst, int tid) {
#pragma unroll
  for (int r = 0; r < 4; ++r) {
    int e = tid + r * 256, d = e >> 3, slot = e & 7;
    glds16(vtg + (size_t)(h * 128 + d) * DD + kt * 64 + ((slot ^ (d & 7)) * 8), dst + e * 8);
  }
}

__global__ __launch_bounds__(256) void attn_k(const bf16* __restrict__ qg, const bf16* __restrict__ kg,
                                              const bf16* __restrict__ vtg, bf16* __restrict__ yg) {
  __shared__ alignas(16) bf16 Ks[2][64 * 128];
  __shared__ alignas(16) bf16 Vt[2][128 * 64];
  // CU-pair load balance: round-robin pairs (x,y) with (x,y+8) on one CU.
  const int h = blockIdx.y;
  const int qb = (blockIdx.y < 8) ? (31 - blockIdx.x) : blockIdx.x;
  const int tid = threadIdx.x, lane = tid & 63, wid = tid >> 6;
  const int l15 = lane & 15, g = lane >> 4, swl = l15 & 7;
  const int qrow = qb * 64 + wid * 16;
  const float scale = 0.08838834764831845f;   // 1/sqrt(128)
  bf16x8 aQ[4];
  {
    const bf16* qp = qg + (size_t)(qrow + l15) * DD + h * 128 + g * 8;
#pragma unroll
    for (int kc = 0; kc < 4; ++kc) aQ[kc] = *(const bf16x8*)(qp + kc * 32);
  }
  f32x4 acc[8] = {};
  float lsum = 0.f;
  const int nkt = qb + 1;                     // tiles of 64 keys
  att_stageK64(kg, h, 0, Ks[0], tid);
  att_stageV64(vtg, h, 0, Vt[0], tid);
  asm volatile("s_waitcnt vmcnt(0)" ::: "memory");
  __builtin_amdgcn_s_barrier();
  for (int kt = 0; kt < nkt; ++kt) {
    const int cur = kt & 1, nb = cur ^ 1;
    // issue next tile's staging early; its landing is guarded at tile end
    if (kt + 1 < nkt) { att_stageK64(kg, h, kt + 1, Ks[nb], tid);
                        att_stageV64(vtg, h, kt + 1, Vt[nb], tid); }
    // S^T = K * Q^T : lane holds S[q=l15][k = kt*64 + 16s + 4g + j]
    f32x4 S[4] = {};
#pragma unroll
    for (int kc = 0; kc < 4; ++kc) {
#pragma unroll
      for (int s = 0; s < 4; ++s) {
        bf16x8 kf = *(const bf16x8*)(Ks[cur] + (16 * s + l15) * 128 + (((kc * 4 + g) ^ swl) * 8));
        S[s] = mfma16(kf, aQ[kc], S[s]);
      }
    }
    const int q = qrow + l15;
    float p[4][4];
    unsigned pw[4][2];
#pragma unroll
    for (int s = 0; s < 4; ++s) {
#pragma unroll
      for (int j = 0; j < 4; ++j) {
        int k0 = kt * 64 + 16 * s + 4 * g + j;
        p[s][j] = (k0 <= q) ? __expf(S[s][j] * scale) : 0.f;
        lsum += p[s][j];
      }
      pw[s][0] = pk2(p[s][0], p[s][1]);
      pw[s][1] = pk2(p[s][2], p[s][3]);
    }
    // repack: aP[ks2] holds P[q=l15][k = ks2*32 + 8g .. +7]
    const int lane_lo = (2 * (g & 1)) * 16 + l15, lane_hi = lane_lo + 16;
    const bool ghi = g >= 2;                   // selects s_src = (g>>1) within each pair
    unsigned a0l = __shfl(pw[0][0], lane_lo), a1l = __shfl(pw[1][0], lane_lo);
    unsigned b0l = __shfl(pw[0][1], lane_lo), b1l = __shfl(pw[1][1], lane_lo);
    unsigned a0h = __shfl(pw[0][0], lane_hi), a1h = __shfl(pw[1][0], lane_hi);
    unsigned b0h = __shfl(pw[0][1], lane_hi), b1h = __shfl(pw[1][1], lane_hi);
    u32x4 av0 = { ghi ? a1l : a0l, ghi ? b1l : b0l, ghi ? a1h : a0h, ghi ? b1h : b0h };
    unsigned c0l = __shfl(pw[2][0], lane_lo), c1l = __shfl(pw[3][0], lane_lo);
    unsigned d0l = __shfl(pw[2][1], lane_lo), d1l = __shfl(pw[3][1], lane_lo);
    unsigned c0h = __shfl(pw[2][0], lane_hi), c1h = __shfl(pw[3][0], lane_hi);
    unsigned d0h = __shfl(pw[2][1], lane_hi), d1h = __shfl(pw[3][1], lane_hi);
    u32x4 av1 = { ghi ? c1l : c0l, ghi ? d1l : d0l, ghi ? c1h : c0h, ghi ? d1h : d0h };
    bf16x8 aP0 = __builtin_bit_cast(bf16x8, av0);
    bf16x8 aP1 = __builtin_bit_cast(bf16x8, av1);
#pragma unroll
    for (int dt = 0; dt < 8; ++dt) {
      int d = dt * 16 + l15;
      bf16x8 bV0 = *(const bf16x8*)(Vt[cur] + d * 64 + ((g ^ (d & 7)) * 8));
      bf16x8 bV1 = *(const bf16x8*)(Vt[cur] + d * 64 + (((4 + g) ^ (d & 7)) * 8));
      acc[dt] = mfma16(aP0, bV0, acc[dt]);
      acc[dt] = mfma16(aP1, bV1, acc[dt]);
    }
    if (kt + 1 < nkt) {
      asm volatile("s_waitcnt vmcnt(0)" ::: "memory");   // next tile landed
      __builtin_amdgcn_s_barrier();
    }
  }
  lsum += __shfl_xor(lsum, 16, 64);
  lsum += __shfl_xor(lsum, 32, 64);
  f32x4 linv;
#pragma unroll
  for (int j = 0; j < 4; ++j) linv[j] = 1.0f / __shfl(lsum, 4 * g + j, 64);
#pragma unroll
  for (int dt = 0; dt < 8; ++dt)
#pragma unroll
    for (int j = 0; j < 4; ++j) {
      int q = qrow + 4 * g + j;
      yg[(size_t)q * DD + h * 128 + dt * 16 + l15] = (bf16)(acc[dt][j] * linv[j]);
    }
}

extern "C" void kernel_launch(void* const* d_in, const int* in_sizes, int n_in,
                              void* d_out, int out_size, void* d_ws, size_t ws_size,
                              hipStream_t stream) {
  const float* x       = (const float*)d_in[0];
  const float* vi      = (const float*)d_in[1];
  const float* x0      = (const float*)d_in[2];
  const float* wq      = (const float*)d_in[3];
  const float* wk      = (const float*)d_in[4];
  const float* wv      = (const float*)d_in[5];
  const float* wo      = (const float*)d_in[6];
  const float* lamb    = (const float*)d_in[7];
  const float* lambdas = (const float*)d_in[8];
  const float* wfc     = (const float*)d_in[9];
  const float* wproj   = (const float*)d_in[10];
  float* out = (float*)d_out;

  (void)hipFuncSetAttribute(reinterpret_cast<const void*>(gemm9_qkv),
                            hipFuncAttributeMaxDynamicSharedMemorySize, G9_LDS);
  (void)hipFuncSetAttribute(reinterpret_cast<const void*>(gemm9_relu),
                            hipFuncAttributeMaxDynamicSharedMemorySize, G9_LDS);
  (void)hipFuncSetAttribute(reinterpret_cast<const void*>(gemm9_part),
                            hipFuncAttributeMaxDynamicSharedMemorySize, G9_LDS);
  (void)hipFuncSetAttribute(reinterpret_cast<const void*>(gemm10_part),
                            hipFuncAttributeMaxDynamicSharedMemorySize, G10_LDS);

  char* wsb = (char*)d_ws;
  size_t off = 0;
  auto alloc = [&](size_t bytes) { void* p = wsb + off; off = (off + bytes + 255) & ~(size_t)255; return p; };
  bf16* wq_b  = (bf16*)alloc(DD2 * 2);
  bf16* wk_b  = (bf16*)alloc(DD2 * 2);
  bf16* wv_b  = (bf16*)alloc(DD2 * 2);
  bf16* wo_b  = (bf16*)alloc(DD2 * 2);
  bf16* wfc_b = (bf16*)alloc(DD2 * 8);   // dead after fc -> proj 4th partial
  bf16* wpj_b = (bf16*)alloc(DD2 * 8);
  // xn..an: 48MB contiguous; doubles as split-K f32 partials when dead
  bf16* xn_b  = (bf16*)alloc(DD2 * 2);
  bf16* q_b   = (bf16*)alloc(DD2 * 2);
  bf16* k_b   = (bf16*)alloc(DD2 * 2);
  bf16* v_b   = (bf16*)alloc(DD2 * 2);
  bf16* y_b   = (bf16*)alloc(DD2 * 2);
  bf16* an_b  = (bf16*)alloc(DD2 * 2);
  float* partA = (float*)xn_b;           // wo: partials 0,1 (xn..v); proj: partials 0..2 (xn..an)
  float* a_f  = (float*)alloc(DD2 * 4);
  bf16* h_b   = (bf16*)alloc(DD2 * 8);
  bf16* vt_b  = h_b;                     // vt dead before fc writes h_b

  pre_k<<<4096, 256, 0, stream>>>(wq, wk, wv, wo, (bf16*)wsb, x, x0, lambdas, xn_b);
  gemm9_qkv<<<dim3(8, 8, 3), 512, G9_LDS, stream>>>(xn_b, wq_b, wk_b, wv_b, q_b, k_b, v_b, vi, lamb);
  ropevt_k<<<18432, 256, 0, stream>>>(q_b, k_b, v_b, vt_b);
  attn_k<<<dim3(32, 16), 256, 0, stream>>>(q_b, k_b, vt_b, y_b);
  gemm10_part<<<dim3(16, 16, 2), 512, G10_LDS, stream>>>(y_b, wo_b, partA, DD, DD, 1024);
  wored_cvt_k<<<4096, 256, 0, stream>>>(partA, a_f, an_b, wfc, wproj, wfc_b);
  gemm9_relu<<<dim3(32, 8), 512, G9_LDS, stream>>>(an_b, wfc_b, h_b, 4 * DD, DD, DD);
  gemm9_part<<<dim3(8, 8, 4), 512, G9_LDS, stream>>>(h_b, wpj_b, partA, (float*)wfc_b, 3, DD, 4 * DD, 2048);
  proj_red<<<2048, 256, 0, stream>>>(partA, (float*)wfc_b, a_f, out);
}

// Round 17
// 360.380 us; speedup vs baseline: 1.0040x; 1.0040x over previous
//
#include <hip/hip_runtime.h>
#include <hip/hip_bf16.h>

typedef __bf16 bf16;
typedef __bf16 bf16x8 __attribute__((ext_vector_type(8)));
typedef float f32x4 __attribute__((ext_vector_type(4)));
typedef unsigned int u32x4 __attribute__((ext_vector_type(4)));

#define DD 2048
#define DD2 4194304ull
#define G9_LDS 131072   // gemm9: 2 buffers x (A[256][64] + B[256][64]) bf16
#define G10_LDS 65536   // gemm10: 2 buffers x (A[128][64] + B[128][64]) bf16

__device__ __forceinline__ void glds16(const void* g, void* l) {
  __builtin_amdgcn_global_load_lds((const __attribute__((address_space(1))) void*)g,
                                   (__attribute__((address_space(3))) void*)l, 16, 0, 0);
}

__device__ __forceinline__ f32x4 mfma16(bf16x8 a, bf16x8 b, f32x4 c) {
  return __builtin_amdgcn_mfma_f32_16x16x32_bf16(a, b, c, 0, 0, 0);
}

__device__ __forceinline__ unsigned pk2(float lo, float hi) {
  unsigned short a = __builtin_bit_cast(unsigned short, (bf16)lo);
  unsigned short b = __builtin_bit_cast(unsigned short, (bf16)hi);
  return (unsigned)a | ((unsigned)b << 16);
}

// cvt helper: grid-stride fp32->bf16 over 4 segments of (1<<seglog) elems, nb blocks
__device__ __forceinline__ void cvt_body(const float* s0, const float* s1, const float* s2,
                                         const float* s3, bf16* dst, int seglog, size_t total,
                                         int bid, int nb) {
  size_t i = ((size_t)bid * 256 + threadIdx.x) * 16;
  const size_t stride = (size_t)nb * 256 * 16;
  for (; i < total; i += stride) {
    int seg = (int)(i >> seglog);
    const float* src = (seg == 0) ? s0 : (seg == 1) ? s1 : (seg == 2) ? s2 : s3;
    size_t loc = i - ((size_t)seg << seglog);
    float4 a0 = *(const float4*)(src + loc);
    float4 a1 = *(const float4*)(src + loc + 4);
    float4 a2 = *(const float4*)(src + loc + 8);
    float4 a3 = *(const float4*)(src + loc + 12);
    bf16x8 o0, o1;
    o0[0] = (bf16)a0.x; o0[1] = (bf16)a0.y; o0[2] = (bf16)a0.z; o0[3] = (bf16)a0.w;
    o0[4] = (bf16)a1.x; o0[5] = (bf16)a1.y; o0[6] = (bf16)a1.z; o0[7] = (bf16)a1.w;
    o1[0] = (bf16)a2.x; o1[1] = (bf16)a2.y; o1[2] = (bf16)a2.z; o1[3] = (bf16)a2.w;
    o1[4] = (bf16)a3.x; o1[5] = (bf16)a3.y; o1[6] = (bf16)a3.z; o1[7] = (bf16)a3.w;
    *(bf16x8*)(dst + i) = o0;
    *(bf16x8*)(dst + i + 8) = o1;
  }
}

// ---------------- pre_k: cvt(wq..wo) [blocks 0..2047]  ||  prenorm-blend [2048..4095] ----------------
__global__ __launch_bounds__(256) void pre_k(const float* __restrict__ wq, const float* __restrict__ wk,
                                             const float* __restrict__ wv, const float* __restrict__ wo,
                                             bf16* __restrict__ wdst,
                                             const float* __restrict__ x, const float* __restrict__ x0,
                                             const float* __restrict__ lambdas, bf16* __restrict__ xn) {
  if (blockIdx.x < 2048) {
    cvt_body(wq, wk, wv, wo, wdst, 22, 4 * DD2, blockIdx.x, 2048);
    return;
  }
  const int t = blockIdx.x - 2048, tid = threadIdx.x;
  const float4* xr = (const float4*)(x + (size_t)t * DD);
  float4 a0 = xr[2 * tid], a1 = xr[2 * tid + 1];
  float v[8] = {a0.x, a0.y, a0.z, a0.w, a1.x, a1.y, a1.z, a1.w};
  const float l0 = lambdas[0], l1 = lambdas[1];
  const float4* yr = (const float4*)(x0 + (size_t)t * DD);
  float4 b0 = yr[2 * tid], b1 = yr[2 * tid + 1];
  float w[8] = {b0.x, b0.y, b0.z, b0.w, b1.x, b1.y, b1.z, b1.w};
#pragma unroll
  for (int i = 0; i < 8; ++i) v[i] = l0 * v[i] + l1 * w[i];
  float ss = 0.f;
#pragma unroll
  for (int i = 0; i < 8; ++i) ss += v[i] * v[i];
#pragma unroll
  for (int off = 1; off < 64; off <<= 1) ss += __shfl_xor(ss, off, 64);
  __shared__ float red[4];
  if ((tid & 63) == 0) red[tid >> 6] = ss;
  __syncthreads();
  ss = red[0] + red[1] + red[2] + red[3];
  const float sc = rsqrtf(ss * (1.0f / DD) + 1.1920928955078125e-07f);
  bf16x8 o;
#pragma unroll
  for (int i = 0; i < 8; ++i) o[i] = (bf16)(v[i] * sc);
  *(bf16x8*)(xn + (size_t)t * DD + tid * 8) = o;
}

// ---------------- ropevt_k: rope [0..16383] || V-transpose [16384..18431] ----------------
__global__ __launch_bounds__(256) void ropevt_k(bf16* __restrict__ qg, bf16* __restrict__ kg,
                                                const bf16* __restrict__ v, bf16* __restrict__ vt) {
  __shared__ alignas(16) bf16 tile[16 * 128];
  if (blockIdx.x < 16384) {
    const int tid = threadIdx.x, lane = tid & 63, wid = tid >> 6;
    const int p = blockIdx.x * 4 + wid;          // [arr(2)][t(2048)][h(16)]
    bf16* base = ((p >> 15) ? kg : qg);
    const int t = (p >> 4) & 2047, hh = p & 15;
    base += (size_t)t * DD + hh * 128;
    float x1 = (float)base[lane], x2 = (float)base[lane + 64];
    float ss = x1 * x1 + x2 * x2;
#pragma unroll
    for (int off = 1; off < 64; off <<= 1) ss += __shfl_xor(ss, off, 64);
    const float sc = rsqrtf(ss * (1.0f / 128.0f) + 1.1920928955078125e-07f);
    x1 *= sc; x2 *= sc;
    const float fr = (float)t * exp2f((float)lane * (-13.287712379549449f / 64.0f));
    const float s = sinf(fr), c = cosf(fr);
    base[lane]      = (bf16)(x1 * c + x2 * s);
    base[lane + 64] = (bf16)(-x1 * s + x2 * c);
    return;
  }
  const int b = blockIdx.x - 16384;              // 0..2047
  const int tb = b & 127, hb = b >> 7, tid = threadIdx.x;
  glds16(v + (size_t)(tb * 16 + (tid >> 4)) * DD + hb * 128 + (tid & 15) * 8, tile + tid * 8);
  __syncthreads();
  const int d_l = tid & 127, tc = tid >> 7;
  bf16x8 o;
#pragma unroll
  for (int i = 0; i < 8; ++i) o[i] = tile[(tc * 8 + i) * 128 + d_l];
  *(bf16x8*)(vt + (size_t)(hb * 128 + d_l) * DD + tb * 16 + tc * 8) = o;
}

// ================ gemm9: 256x256 tile, 8-wave deep pipeline (R7) ================
__device__ __forceinline__ void g9_stageA(const bf16* A, int Kstride, int row0, int k0,
                                          bf16* buf, int hm, int tid) {
#pragma unroll
  for (int i = 0; i < 2; ++i) {
    int e = tid + i * 512;                 // [0,1024): prl = e>>3, slot = e&7
    int prl = e >> 3, slot = e & 7;
    int wm = prl >> 6, r63 = prl & 63;
    glds16(A + (size_t)(row0 + wm * 128 + hm * 64 + r63) * Kstride + k0 + ((slot ^ (prl & 7)) * 8),
           buf + hm * 8192 + e * 8);
  }
}
__device__ __forceinline__ void g9_stageB(const bf16* B, int Kstride, int col0, int k0,
                                          bf16* buf, int hn, int tid) {
#pragma unroll
  for (int i = 0; i < 2; ++i) {
    int e = tid + i * 512;
    int pbl = e >> 3, slot = e & 7;
    int wn = pbl >> 5, q = pbl & 31;
    glds16(B + (size_t)(col0 + wn * 64 + hn * 32 + q) * Kstride + k0 + ((slot ^ (pbl & 7)) * 8),
           buf + 16384 + hn * 8192 + e * 8);
  }
}

__device__ __forceinline__ void gemm9_core(const bf16* __restrict__ A, const bf16* __restrict__ B,
                                           int Kstride, int Klen, int row0, int col0,
                                           bf16* smem, f32x4 (&acc)[8][4]) {
  const int tid = threadIdx.x, lane = tid & 63, wid = tid >> 6;
  const int wm = wid >> 2, wn = wid & 3;
  const int l15 = lane & 15, g = lane >> 4;
  const int sw = l15 & 7;
  const int NT = Klen >> 6;
  g9_stageA(A, Kstride, row0, 0, smem, 0, tid);
  g9_stageB(B, Kstride, col0, 0, smem, 0, tid);
  g9_stageB(B, Kstride, col0, 0, smem, 1, tid);
  g9_stageA(A, Kstride, row0, 0, smem, 1, tid);
  g9_stageA(A, Kstride, row0, 64, smem + 32768, 0, tid);
  g9_stageB(B, Kstride, col0, 64, smem + 32768, 0, tid);
  asm volatile("s_waitcnt vmcnt(8)" ::: "memory");
  __builtin_amdgcn_s_barrier();

  bf16x8 a[4][2], b0[2][2], b1[2][2];
  for (int t = 0; t < NT; ++t) {
    bf16* cb = smem + (t & 1) * 32768;
    bf16* nb = smem + ((t + 1) & 1) * 32768;
    const bool s1 = (t + 1) < NT, s2 = (t + 2) < NT;
    // ---- P1
#pragma unroll
    for (int mm = 0; mm < 4; ++mm)
#pragma unroll
      for (int ks = 0; ks < 2; ++ks)
        a[mm][ks] = *(const bf16x8*)(cb + (wm * 64 + mm * 16 + l15) * 64 + (((ks * 4 + g) ^ sw) * 8));
#pragma unroll
    for (int nn = 0; nn < 2; ++nn)
#pragma unroll
      for (int ks = 0; ks < 2; ++ks)
        b0[nn][ks] = *(const bf16x8*)(cb + 16384 + (wn * 32 + nn * 16 + l15) * 64 + (((ks * 4 + g) ^ sw) * 8));
    if (s1) { g9_stageB(B, Kstride, col0, (t + 1) << 6, nb, 1, tid);
              g9_stageA(A, Kstride, row0, (t + 1) << 6, nb, 1, tid);
              asm volatile("s_waitcnt vmcnt(8)" ::: "memory"); }
    else    { asm volatile("s_waitcnt vmcnt(0)" ::: "memory"); }
    __builtin_amdgcn_s_barrier();
    __builtin_amdgcn_s_setprio(1);
#pragma unroll
    for (int mm = 0; mm < 4; ++mm)
#pragma unroll
      for (int nn = 0; nn < 2; ++nn)
#pragma unroll
        for (int ks = 0; ks < 2; ++ks)
          acc[mm][nn] = mfma16(a[mm][ks], b0[nn][ks], acc[mm][nn]);
    __builtin_amdgcn_s_setprio(0);
    // ---- P2
#pragma unroll
    for (int nn = 0; nn < 2; ++nn)
#pragma unroll
      for (int ks = 0; ks < 2; ++ks)
        b1[nn][ks] = *(const bf16x8*)(cb + 16384 + 8192 + (wn * 32 + nn * 16 + l15) * 64 + (((ks * 4 + g) ^ sw) * 8));
    __builtin_amdgcn_s_barrier();
    __builtin_amdgcn_s_setprio(1);
#pragma unroll
    for (int mm = 0; mm < 4; ++mm)
#pragma unroll
      for (int nn = 0; nn < 2; ++nn)
#pragma unroll
        for (int ks = 0; ks < 2; ++ks)
          acc[mm][2 + nn] = mfma16(a[mm][ks], b1[nn][ks], acc[mm][2 + nn]);
    __builtin_amdgcn_s_setprio(0);
    // ---- P3
#pragma unroll
    for (int mm = 0; mm < 4; ++mm)
#pragma unroll
      for (int ks = 0; ks < 2; ++ks)
        a[mm][ks] = *(const bf16x8*)(cb + 8192 + (wm * 64 + mm * 16 + l15) * 64 + (((ks * 4 + g) ^ sw) * 8));
    __builtin_amdgcn_s_barrier();
    __builtin_amdgcn_s_setprio(1);
#pragma unroll
    for (int mm = 0; mm < 4; ++mm)
#pragma unroll
      for (int nn = 0; nn < 2; ++nn)
#pragma unroll
        for (int ks = 0; ks < 2; ++ks)
          acc[4 + mm][nn] = mfma16(a[mm][ks], b0[nn][ks], acc[4 + mm][nn]);
    __builtin_amdgcn_s_setprio(0);
    // ---- P4
    if (s2) { g9_stageA(A, Kstride, row0, (t + 2) << 6, cb, 0, tid);
              g9_stageB(B, Kstride, col0, (t + 2) << 6, cb, 0, tid);
              asm volatile("s_waitcnt vmcnt(8)" ::: "memory"); }
    else if (s1) { asm volatile("s_waitcnt vmcnt(4)" ::: "memory"); }
    __builtin_amdgcn_s_barrier();
    __builtin_amdgcn_s_setprio(1);
#pragma unroll
    for (int mm = 0; mm < 4; ++mm)
#pragma unroll
      for (int nn = 0; nn < 2; ++nn)
#pragma unroll
        for (int ks = 0; ks < 2; ++ks)
          acc[4 + mm][2 + nn] = mfma16(a[mm][ks], b1[nn][ks], acc[4 + mm][2 + nn]);
    __builtin_amdgcn_s_setprio(0);
  }
}

#define GEMM9_EPI(STMT)                                                        \
  { const int lane_ = threadIdx.x & 63, wid_ = threadIdx.x >> 6;               \
    const int l15_ = lane_ & 15, g_ = lane_ >> 4;                              \
    const int wm_ = wid_ >> 2, wn_ = wid_ & 3;                                 \
    _Pragma("unroll") for (int m = 0; m < 8; ++m)                              \
    _Pragma("unroll") for (int n = 0; n < 4; ++n)                              \
    _Pragma("unroll") for (int j = 0; j < 4; ++j) {                            \
      int grow = row0 + wm_ * 128 + (m >> 2) * 64 + (m & 3) * 16 + g_ * 4 + j; \
      int gcol = col0 + wn_ * 64 + (n >> 1) * 32 + (n & 1) * 16 + l15_;        \
      float vacc = acc[m][n][j];                                               \
      STMT; } }

__global__ __launch_bounds__(512, 1) void gemm9_qkv(const bf16* __restrict__ A,
    const bf16* __restrict__ Wq, const bf16* __restrict__ Wk, const bf16* __restrict__ Wv,
    bf16* __restrict__ oq, bf16* __restrict__ ok, bf16* __restrict__ ov,
    const float* __restrict__ vi, const float* __restrict__ lambp) {
  extern __shared__ bf16 smem9[];
  const int z = blockIdx.z;
  const bf16* B = (z == 0) ? Wq : (z == 1) ? Wk : Wv;
  bf16* out = (z == 0) ? oq : (z == 1) ? ok : ov;
  const int row0 = blockIdx.y * 256, col0 = blockIdx.x * 256;
  f32x4 acc[8][4] = {};
  gemm9_core(A, B, DD, DD, row0, col0, smem9, acc);
  if (z < 2) {
    GEMM9_EPI( out[(size_t)grow * DD + gcol] = (bf16)vacc; )
  } else {
    const float lam = *lambp;
    GEMM9_EPI( out[(size_t)grow * DD + gcol] =
                 (bf16)((1.0f - lam) * vacc + lam * vi[(size_t)grow * DD + gcol]); )
  }
}

__global__ __launch_bounds__(512, 1) void gemm9_relu(const bf16* __restrict__ A, const bf16* __restrict__ B,
                                                     bf16* __restrict__ out, int N, int Kstride, int Klen) {
  extern __shared__ bf16 smem9[];
  const int row0 = blockIdx.y * 256, col0 = blockIdx.x * 256;
  f32x4 acc[8][4] = {};
  gemm9_core(A, B, Kstride, Klen, row0, col0, smem9, acc);
  GEMM9_EPI( float r = fmaxf(vacc, 0.f); out[(size_t)grow * N + gcol] = (bf16)(r * r); )
}

__global__ __launch_bounds__(512, 1) void gemm9_part(const bf16* __restrict__ A, const bf16* __restrict__ B,
                                                     float* __restrict__ o1, float* __restrict__ o2,
                                                     int zsw, int N, int Kstride, int Klen) {
  extern __shared__ bf16 smem9[];
  const int row0 = blockIdx.y * 256, col0 = blockIdx.x * 256;
  const int z = blockIdx.z, kofs = z * Klen;
  float* out = (z < zsw) ? (o1 + (size_t)z * DD2) : (o2 + (size_t)(z - zsw) * DD2);
  f32x4 acc[8][4] = {};
  gemm9_core(A + kofs, B + kofs, Kstride, Klen, row0, col0, smem9, acc);
  GEMM9_EPI( out[(size_t)grow * N + gcol] = vacc; )
}

// ================ gemm10: 128x128 tile, 8-wave, 2-blocks/CU — wo only ================
__device__ __forceinline__ void g10_stageA(const bf16* A, int Kstride, int row0, int k0,
                                           bf16* buf, int hm, int tid) {
  int prl = tid >> 3, slot = tid & 7;
  int wmb = prl >> 5, r31 = prl & 31;
  glds16(A + (size_t)(row0 + wmb * 64 + hm * 32 + r31) * Kstride + k0 + ((slot ^ (prl & 7)) * 8),
         buf + hm * 4096 + tid * 8);
}
__device__ __forceinline__ void g10_stageB(const bf16* B, int Kstride, int col0, int k0,
                                           bf16* buf, int hn, int tid) {
  int pbl = tid >> 3, slot = tid & 7;
  int wnb = pbl >> 4, c15 = pbl & 15;
  glds16(B + (size_t)(col0 + wnb * 32 + hn * 16 + c15) * Kstride + k0 + ((slot ^ (pbl & 7)) * 8),
         buf + 8192 + hn * 4096 + tid * 8);
}

__device__ __forceinline__ void gemm10_core(const bf16* __restrict__ A, const bf16* __restrict__ B,
                                            int Kstride, int Klen, int row0, int col0,
                                            bf16* smem, f32x4 (&acc)[4][2]) {
  const int tid = threadIdx.x, lane = tid & 63, wid = tid >> 6;
  const int wm = wid >> 2, wn = wid & 3;
  const int l15 = lane & 15, g = lane >> 4;
  const int NT = Klen >> 6;
  g10_stageA(A, Kstride, row0, 0, smem, 0, tid);
  g10_stageB(B, Kstride, col0, 0, smem, 0, tid);
  g10_stageB(B, Kstride, col0, 0, smem, 1, tid);
  g10_stageA(A, Kstride, row0, 0, smem, 1, tid);
  asm volatile("s_waitcnt vmcnt(2)" ::: "memory");
  __builtin_amdgcn_s_barrier();

  bf16x8 a[2][2], b0[2], b1[2];
  for (int t = 0; t < NT; ++t) {
    bf16* cb = smem + (t & 1) * 16384;
    bf16* nb = smem + ((t + 1) & 1) * 16384;
    const int kst = (t + 1) << 6;
    const bool st = (t + 1) < NT;
    // ---- P1
#pragma unroll
    for (int mm = 0; mm < 2; ++mm)
#pragma unroll
      for (int ks = 0; ks < 2; ++ks) {
        int pr = wm * 32 + mm * 16 + l15;
        a[mm][ks] = *(const bf16x8*)(cb + pr * 64 + (((ks * 4 + g) ^ (pr & 7)) * 8));
      }
#pragma unroll
    for (int ks = 0; ks < 2; ++ks) {
      int pb = wn * 16 + l15;
      b0[ks] = *(const bf16x8*)(cb + 8192 + pb * 64 + (((ks * 4 + g) ^ (pb & 7)) * 8));
    }
    if (st) { g10_stageA(A, Kstride, row0, kst, nb, 0, tid);
              asm volatile("s_waitcnt vmcnt(2)" ::: "memory"); }
    else    { asm volatile("s_waitcnt vmcnt(1)" ::: "memory"); }
    __builtin_amdgcn_s_barrier();
    __builtin_amdgcn_s_setprio(1);
#pragma unroll
    for (int mm = 0; mm < 2; ++mm)
#pragma unroll
      for (int ks = 0; ks < 2; ++ks)
        acc[mm][0] = mfma16(a[mm][ks], b0[ks], acc[mm][0]);
    __builtin_amdgcn_s_setprio(0);
    // ---- P2
#pragma unroll
    for (int ks = 0; ks < 2; ++ks) {
      int pb = wn * 16 + l15;
      b1[ks] = *(const bf16x8*)(cb + 8192 + 4096 + pb * 64 + (((ks * 4 + g) ^ (pb & 7)) * 8));
    }
    if (st) { g10_stageB(B, Kstride, col0, kst, nb, 0, tid);
              asm volatile("s_waitcnt vmcnt(2)" ::: "memory"); }
    else    { asm volatile("s_waitcnt vmcnt(0)" ::: "memory"); }
    __builtin_amdgcn_s_barrier();
    __builtin_amdgcn_s_setprio(1);
#pragma unroll
    for (int mm = 0; mm < 2; ++mm)
#pragma unroll
      for (int ks = 0; ks < 2; ++ks)
        acc[mm][1] = mfma16(a[mm][ks], b1[ks], acc[mm][1]);
    __builtin_amdgcn_s_setprio(0);
    // ---- P3
#pragma unroll
    for (int mm = 0; mm < 2; ++mm)
#pragma unroll
      for (int ks = 0; ks < 2; ++ks) {
        int pr = 64 + wm * 32 + mm * 16 + l15;
        a[mm][ks] = *(const bf16x8*)(cb + pr * 64 + (((ks * 4 + g) ^ (pr & 7)) * 8));
      }
    if (st) g10_stageB(B, Kstride, col0, kst, nb, 1, tid);
    __builtin_amdgcn_s_barrier();
    __builtin_amdgcn_s_setprio(1);
#pragma unroll
    for (int mm = 0; mm < 2; ++mm)
#pragma unroll
      for (int ks = 0; ks < 2; ++ks)
        acc[2 + mm][0] = mfma16(a[mm][ks], b0[ks], acc[2 + mm][0]);
    __builtin_amdgcn_s_setprio(0);
    // ---- P4
    if (st) { g10_stageA(A, Kstride, row0, kst, nb, 1, tid);
              asm volatile("s_waitcnt vmcnt(2)" ::: "memory"); }
    __builtin_amdgcn_s_barrier();
    __builtin_amdgcn_s_setprio(1);
#pragma unroll
    for (int mm = 0; mm < 2; ++mm)
#pragma unroll
      for (int ks = 0; ks < 2; ++ks)
        acc[2 + mm][1] = mfma16(a[mm][ks], b1[ks], acc[2 + mm][1]);
    __builtin_amdgcn_s_setprio(0);
  }
}

#define GEMM10_EPI(STMT)                                                       \
  { const int lane_ = threadIdx.x & 63, wid_ = threadIdx.x >> 6;               \
    const int l15_ = lane_ & 15, g_ = lane_ >> 4;                              \
    const int wm_ = wid_ >> 2, wn_ = wid_ & 3;                                 \
    _Pragma("unroll") for (int m = 0; m < 4; ++m)                              \
    _Pragma("unroll") for (int n = 0; n < 2; ++n)                              \
    _Pragma("unroll") for (int j = 0; j < 4; ++j) {                            \
      int grow = row0 + wm_ * 64 + (m >> 1) * 32 + (m & 1) * 16 + g_ * 4 + j;  \
      int gcol = col0 + wn_ * 32 + n * 16 + l15_;                              \
      float vacc = acc[m][n][j];                                               \
      STMT; } }

__global__ __launch_bounds__(512, 4) void gemm10_part(const bf16* __restrict__ A, const bf16* __restrict__ B,
                                                      float* __restrict__ o1, int N, int Kstride, int Klen) {
  extern __shared__ bf16 smem10[];
  const int row0 = blockIdx.y * 128, col0 = blockIdx.x * 128;
  const int kofs = blockIdx.z * Klen;
  float* out = o1 + (size_t)blockIdx.z * DD2;
  f32x4 acc[4][2] = {};
  gemm10_core(A + kofs, B + kofs, Kstride, Klen, row0, col0, smem10, acc);
  GEMM10_EPI( out[(size_t)grow * N + gcol] = vacc; )
}

// -------- wored_cvt_k: wo_red+prenorm [blocks 0..2047] || cvt(wfc,wproj) [2048..4095] --------
__global__ __launch_bounds__(256) void wored_cvt_k(const float* __restrict__ pa,
                                                   float* __restrict__ a_f, bf16* __restrict__ an,
                                                   const float* __restrict__ wfc, const float* __restrict__ wpj,
                                                   bf16* __restrict__ wdst) {
  if (blockIdx.x >= 2048) {
    cvt_body(wfc, wpj, wfc, wfc, wdst, 24, 8 * DD2, blockIdx.x - 2048, 2048);
    return;
  }
  const int t = blockIdx.x, tid = threadIdx.x;
  const size_t base = (size_t)t * DD + tid * 8;
  float v[8];
#pragma unroll
  for (int h = 0; h < 2; ++h) {
    size_t i = base + h * 4;
    float4 r0 = *(const float4*)(pa + i);
    float4 r1 = *(const float4*)(pa + DD2 + i);
    v[h*4+0] = r0.x + r1.x;
    v[h*4+1] = r0.y + r1.y;
    v[h*4+2] = r0.z + r1.z;
    v[h*4+3] = r0.w + r1.w;
  }
  *(float4*)(a_f + base)     = make_float4(v[0], v[1], v[2], v[3]);
  *(float4*)(a_f + base + 4) = make_float4(v[4], v[5], v[6], v[7]);
  float ss = 0.f;
#pragma unroll
  for (int i = 0; i < 8; ++i) ss += v[i] * v[i];
#pragma unroll
  for (int off = 1; off < 64; off <<= 1) ss += __shfl_xor(ss, off, 64);
  __shared__ float red[4];
  if ((tid & 63) == 0) red[tid >> 6] = ss;
  __syncthreads();
  ss = red[0] + red[1] + red[2] + red[3];
  const float sc = rsqrtf(ss * (1.0f / DD) + 1.1920928955078125e-07f);
  bf16x8 o;
#pragma unroll
  for (int i = 0; i < 8; ++i) o[i] = (bf16)(v[i] * sc);
  *(bf16x8*)(an + base) = o;
}

// proj reduce: 4 partials (pa[0..2], pw) + residual a_f
__global__ __launch_bounds__(256) void proj_red(const float* __restrict__ pa, const float* __restrict__ pw,
                                                const float* __restrict__ a_f, float* __restrict__ out) {
  const size_t base = ((size_t)blockIdx.x * 256 + threadIdx.x) * 8;
#pragma unroll
  for (int h = 0; h < 2; ++h) {
    size_t i = base + h * 4;
    float4 r = *(const float4*)(a_f + i);
    float4 u = *(const float4*)(pa + i);
    float4 w = *(const float4*)(pa + DD2 + i);
    float4 z = *(const float4*)(pa + 2 * DD2 + i);
    float4 y = *(const float4*)(pw + i);
    *(float4*)(out + i) = make_float4(r.x + u.x + w.x + z.x + y.x,
                                      r.y + u.y + w.y + z.y + y.y,
                                      r.z + u.z + w.z + z.z + y.z,
                                      r.w + u.w + w.w + z.w + y.w);
  }
}

// ---------------- causal flash attention (KB=32, 3-buffer — best measured) ----------------
__device__ __forceinline__ void att_stageK(const bf16* kg, int h, int kt, bf16* dst, int tid) {
#pragma unroll
  for (int r = 0; r < 2; ++r) {
    int e = tid + r * 256, row = e >> 4, slot = e & 15;
    glds16(kg + (size_t)(kt * 32 + row) * DD + h * 128 + ((slot ^ (row & 7)) * 8), dst + e * 8);
  }
}
__device__ __forceinline__ void att_stageV(const bf16* vtg, int h, int kt, bf16* dst, int tid) {
#pragma unroll
  for (int r = 0; r < 2; ++r) {
    int e = tid + r * 256, d = e >> 2, slot = e & 3;
    glds16(vtg + (size_t)(h * 128 + d) * DD + kt * 32 + ((slot ^ ((d >> 1) & 3)) * 8), dst + e * 8);
  }
}

__global__ __launch_bounds__(256) void attn_k(const bf16* __restrict__ qg, const bf16* __restrict__ kg,
                                              const bf16* __restrict__ vtg, bf16* __restrict__ yg) {
  __shared__ alignas(16) bf16 Ks[3][32 * 128];
  __shared__ alignas(16) bf16 Vt[3][128 * 32];
  // CU-pair load balance: round-robin pairs (x,y) with (x,y+8) on one CU.
  const int h = blockIdx.y;
  const int qb = (blockIdx.y < 8) ? (31 - blockIdx.x) : blockIdx.x;
  const int tid = threadIdx.x, lane = tid & 63, wid = tid >> 6;
  const int l15 = lane & 15, g = lane >> 4, swl = l15 & 7;
  const int qrow = qb * 64 + wid * 16;
  const float scale = 0.08838834764831845f;   // 1/sqrt(128)
  bf16x8 aQ[4];
  {
    const bf16* qp = qg + (size_t)(qrow + l15) * DD + h * 128 + g * 8;
#pragma unroll
    for (int kc = 0; kc < 4; ++kc) aQ[kc] = *(const bf16x8*)(qp + kc * 32);
  }
  f32x4 acc[8] = {};
  float lsum = 0.f;
  const int nkt = qb * 2 + 2;
  att_stageK(kg, h, 0, Ks[0], tid);
  att_stageV(vtg, h, 0, Vt[0], tid);
  att_stageK(kg, h, 1, Ks[1], tid);
  att_stageV(vtg, h, 1, Vt[1], tid);
  asm volatile("s_waitcnt vmcnt(4)" ::: "memory");
  __builtin_amdgcn_s_barrier();
  int cur = 0;
  for (int kt = 0; kt < nkt; ++kt) {
    const int kbase = kt * 32;
    const int nb = (cur >= 1) ? cur - 1 : 2;
    bf16x8 kf0[4], kf1[4];
#pragma unroll
    for (int kc = 0; kc < 4; ++kc) {
      kf0[kc] = *(const bf16x8*)(Ks[cur] + l15 * 128 + (((kc * 4 + g) ^ swl) * 8));
      kf1[kc] = *(const bf16x8*)(Ks[cur] + (16 + l15) * 128 + (((kc * 4 + g) ^ swl) * 8));
    }
    if (kt + 2 < nkt) { att_stageK(kg, h, kt + 2, Ks[nb], tid);
                        att_stageV(vtg, h, kt + 2, Vt[nb], tid); }
    f32x4 S0 = {}, S1 = {};
#pragma unroll
    for (int kc = 0; kc < 4; ++kc) {
      S0 = mfma16(kf0[kc], aQ[kc], S0);
      S1 = mfma16(kf1[kc], aQ[kc], S1);
    }
    const int q = qrow + l15;
    float p0[4], p1[4];
#pragma unroll
    for (int j = 0; j < 4; ++j) {
      int k0 = kbase + 4 * g + j;
      p0[j] = (k0 <= q) ? __expf(S0[j] * scale) : 0.f;
      p1[j] = (k0 + 16 <= q) ? __expf(S1[j] * scale) : 0.f;
      lsum += p0[j] + p1[j];
    }
    unsigned w0 = pk2(p0[0], p0[1]), w1 = pk2(p0[2], p0[3]);
    unsigned w2 = pk2(p1[0], p1[1]), w3 = pk2(p1[2], p1[3]);
    const int s0l = (g & 1) * 32 + l15, s1l = s0l + 16;
    const bool hi = g >= 2;
    unsigned t00 = __shfl(w0, s0l, 64), t10 = __shfl(w1, s0l, 64);
    unsigned t01 = __shfl(w0, s1l, 64), t11 = __shfl(w1, s1l, 64);
    unsigned u00 = __shfl(w2, s0l, 64), u10 = __shfl(w3, s0l, 64);
    unsigned u01 = __shfl(w2, s1l, 64), u11 = __shfl(w3, s1l, 64);
    u32x4 av = { hi ? u00 : t00, hi ? u10 : t10, hi ? u01 : t01, hi ? u11 : t11 };
    bf16x8 aP = __builtin_bit_cast(bf16x8, av);
#pragma unroll
    for (int dt = 0; dt < 8; ++dt) {
      int d = dt * 16 + l15;
      bf16x8 bV = *(const bf16x8*)(Vt[cur] + d * 32 + ((g ^ ((d >> 1) & 3)) * 8));
      acc[dt] = mfma16(aP, bV, acc[dt]);
    }
    if (kt + 1 < nkt) {
      if (kt + 2 < nkt) { asm volatile("s_waitcnt vmcnt(4)" ::: "memory"); }
      else              { asm volatile("s_waitcnt vmcnt(0)" ::: "memory"); }
      __builtin_amdgcn_s_barrier();
    }
    cur = (cur == 2) ? 0 : cur + 1;
  }
  lsum += __shfl_xor(lsum, 16, 64);
  lsum += __shfl_xor(lsum, 32, 64);
  f32x4 linv;
#pragma unroll
  for (int j = 0; j < 4; ++j) linv[j] = 1.0f / __shfl(lsum, 4 * g + j, 64);
#pragma unroll
  for (int dt = 0; dt < 8; ++dt)
#pragma unroll
    for (int j = 0; j < 4; ++j) {
      int q = qrow + 4 * g + j;
      yg[(size_t)q * DD + h * 128 + dt * 16 + l15] = (bf16)(acc[dt][j] * linv[j]);
    }
}

extern "C" void kernel_launch(void* const* d_in, const int* in_sizes, int n_in,
                              void* d_out, int out_size, void* d_ws, size_t ws_size,
                              hipStream_t stream) {
  const float* x       = (const float*)d_in[0];
  const float* vi      = (const float*)d_in[1];
  const float* x0      = (const float*)d_in[2];
  const float* wq      = (const float*)d_in[3];
  const float* wk      = (const float*)d_in[4];
  const float* wv      = (const float*)d_in[5];
  const float* wo      = (const float*)d_in[6];
  const float* lamb    = (const float*)d_in[7];
  const float* lambdas = (const float*)d_in[8];
  const float* wfc     = (const float*)d_in[9];
  const float* wproj   = (const float*)d_in[10];
  float* out = (float*)d_out;

  (void)hipFuncSetAttribute(reinterpret_cast<const void*>(gemm9_qkv),
                            hipFuncAttributeMaxDynamicSharedMemorySize, G9_LDS);
  (void)hipFuncSetAttribute(reinterpret_cast<const void*>(gemm9_relu),
                            hipFuncAttributeMaxDynamicSharedMemorySize, G9_LDS);
  (void)hipFuncSetAttribute(reinterpret_cast<const void*>(gemm9_part),
                            hipFuncAttributeMaxDynamicSharedMemorySize, G9_LDS);
  (void)hipFuncSetAttribute(reinterpret_cast<const void*>(gemm10_part),
                            hipFuncAttributeMaxDynamicSharedMemorySize, G10_LDS);

  char* wsb = (char*)d_ws;
  size_t off = 0;
  auto alloc = [&](size_t bytes) { void* p = wsb + off; off = (off + bytes + 255) & ~(size_t)255; return p; };
  bf16* wq_b  = (bf16*)alloc(DD2 * 2);
  bf16* wk_b  = (bf16*)alloc(DD2 * 2);
  bf16* wv_b  = (bf16*)alloc(DD2 * 2);
  bf16* wo_b  = (bf16*)alloc(DD2 * 2);
  bf16* wfc_b = (bf16*)alloc(DD2 * 8);   // dead after fc -> proj 4th partial
  bf16* wpj_b = (bf16*)alloc(DD2 * 8);
  // xn..an: 48MB contiguous; doubles as split-K f32 partials when dead
  bf16* xn_b  = (bf16*)alloc(DD2 * 2);
  bf16* q_b   = (bf16*)alloc(DD2 * 2);
  bf16* k_b   = (bf16*)alloc(DD2 * 2);
  bf16* v_b   = (bf16*)alloc(DD2 * 2);
  bf16* y_b   = (bf16*)alloc(DD2 * 2);
  bf16* an_b  = (bf16*)alloc(DD2 * 2);
  float* partA = (float*)xn_b;           // wo: partials 0,1 (xn..v); proj: partials 0..2 (xn..an)
  float* a_f  = (float*)alloc(DD2 * 4);
  bf16* h_b   = (bf16*)alloc(DD2 * 8);
  bf16* vt_b  = h_b;                     // vt dead before fc writes h_b

  pre_k<<<4096, 256, 0, stream>>>(wq, wk, wv, wo, (bf16*)wsb, x, x0, lambdas, xn_b);
  gemm9_qkv<<<dim3(8, 8, 3), 512, G9_LDS, stream>>>(xn_b, wq_b, wk_b, wv_b, q_b, k_b, v_b, vi, lamb);
  ropevt_k<<<18432, 256, 0, stream>>>(q_b, k_b, v_b, vt_b);
  attn_k<<<dim3(32, 16), 256, 0, stream>>>(q_b, k_b, vt_b, y_b);
  gemm10_part<<<dim3(16, 16, 2), 512, G10_LDS, stream>>>(y_b, wo_b, partA, DD, DD, 1024);
  wored_cvt_k<<<4096, 256, 0, stream>>>(partA, a_f, an_b, wfc, wproj, wfc_b);
  gemm9_relu<<<dim3(32, 8), 512, G9_LDS, stream>>>(an_b, wfc_b, h_b, 4 * DD, DD, DD);
  gemm9_part<<<dim3(8, 8, 4), 512, G9_LDS, stream>>>(h_b, wpj_b, partA, (float*)wfc_b, 3, DD, 4 * DD, 2048);
  proj_red<<<2048, 256, 0, stream>>>(partA, (float*)wfc_b, a_f, out);
}